// Round 12
// baseline (154.615 us; speedup 1.0000x reference)
//
#include <hip/hip_runtime.h>
#include <math.h>

#define SLOPE  0.2f
#define NB     32
#define LEN    512
#define LATENT 64
#define HID    64
#define IN_DIM 129
#define TROWS  514
#define NTOT   (NB * LEN)      // 16384

typedef __attribute__((ext_vector_type(8)))  short bf16x8;
typedef __attribute__((ext_vector_type(16))) float f32x16;
typedef __attribute__((ext_vector_type(4)))  float f32x4;

struct alignas(8)  US4 { unsigned short x, y, z, w; };
struct alignas(16) US8 { unsigned short s[8]; };

// round-to-nearest bf16 split: v = hi + lo + O(2^-18 v)
__device__ inline void bsplit(float v, unsigned short& hi, unsigned short& lo) {
    unsigned int u  = __builtin_bit_cast(unsigned int, v);
    unsigned int hb = (u + 0x7fffu + ((u >> 16) & 1u)) >> 16;
    hi = (unsigned short)hb;
    float fh = __builtin_bit_cast(float, hb << 16);
    float r  = v - fh;                      // exact (Sterbenz)
    unsigned int u2 = __builtin_bit_cast(unsigned int, r);
    lo = (unsigned short)((u2 + 0x7fffu + ((u2 >> 16) & 1u)) >> 16);
}

// pre-pass, WRITE-coalesced: thread t owns one 16B fragment slot of
// W1f[l][i][ks][part][lane][8]  (t = ((((l*2+i)*8+ks)*2+part)*64+lane)).
// Reads gather from W1g (L2-cached); writes are linear 16B. 512 blocks.
__global__ __launch_bounds__(256)
void conv_w1(const float* __restrict__ W1g, unsigned short* __restrict__ W1f,
             float* __restrict__ W1t, float* __restrict__ out_lad) {
    const int t = blockIdx.x * 256 + threadIdx.x;   // 0..131071
    if (t < NTOT) out_lad[t] = 0.f;
    if (t < 4096) W1t[t] = W1g[(size_t)t * IN_DIM + 128];
    const int lane = t & 63;
    const int part = (t >> 6) & 1;
    const int ks   = (t >> 7) & 7;
    const int i    = (t >> 10) & 1;
    const int l    = t >> 11;                       // 0..63
    const int hi32 = lane >> 5, r32 = lane & 31;
    const int row  = l * 64 + i * 32 + r32;         // <= 4095
    const int k0   = ks * 16 + hi32 * 8;            // <= 120
    const float* src = W1g + (size_t)row * IN_DIM + k0;
    US8 v;
    #pragma unroll
    for (int e = 0; e < 8; ++e) {
        unsigned short h, lo;
        bsplit(src[e], h, lo);
        v.s[e] = part ? lo : h;
    }
    *reinterpret_cast<US8*>(W1f + (size_t)t * 8) = v;
}

// 256 thr / 4 waves; block = one 64-row n-tile x 32 latents (8 quad-iters).
// Wave-tile 64h x 64n (acc[2][2] = 4 indep chains, 2x A-reuse). x staged once;
// quad loop barrier-free; A from L2 per quad. grid 512 = 2 blocks/CU.
__global__ __launch_bounds__(256, 3)
void fused_mfma(const float* __restrict__ xg,
                const float* __restrict__ b1g, const float* __restrict__ W2g,
                const float* __restrict__ b2g,
                const unsigned short* __restrict__ W1f,
                const float* __restrict__ W1t,
                float* __restrict__ out_res, float* __restrict__ out_lad)
{
    __shared__ unsigned short sXh[66][72];   // x hi, stride 144B
    __shared__ unsigned short sXl[66][72];   // x lo
    __shared__ float sR[64][33];             // residual transpose (pad 33)
    __shared__ float sJ[64][5];              // per-wn jacobian logsums (pad 5)

    const int tid   = threadIdx.x;
    const int tile  = blockIdx.x & 255;      // 0..255 : 64-row n-tile
    const int lhalf = blockIdx.x >> 8;       // 0..1   : latent half
    const int pt    = tile >> 3;             // batch row
    const int s     = tile & 7;
    const size_t xrow0 = (size_t)pt * TROWS + s * 64;
    const size_t nbase = (size_t)tile * 64;

    // ---- stage x tile once: 66 rows x 64, bf16 hi/lo ----
    for (int i = tid; i < 66 * 16; i += 256) {
        const int row = i >> 4, c4 = (i & 15) << 2;
        const float4 v = *reinterpret_cast<const float4*>(
            xg + (xrow0 + row) * LATENT + c4);
        unsigned short h0,h1,h2,h3, l0,l1,l2,l3;
        bsplit(v.x, h0, l0); bsplit(v.y, h1, l1);
        bsplit(v.z, h2, l2); bsplit(v.w, h3, l3);
        *reinterpret_cast<US4*>(&sXh[row][c4]) = US4{h0, h1, h2, h3};
        *reinterpret_cast<US4*>(&sXl[row][c4]) = US4{l0, l1, l2, l3};
    }
    __syncthreads();   // single barrier; sXh/sXl read-only afterwards

    const int wn   = tid >> 6;               // 0..3
    const int lane = tid & 63;
    const int r32  = lane & 31;
    const int hi32 = lane >> 5;

    float jlog0 = 0.f, jlog1 = 0.f, jprod0 = 1.f, jprod1 = 1.f;

    #pragma unroll 1
    for (int q = 0; q < 8; ++q) {
        const int l = lhalf * 32 + q * 4 + wn;
        const unsigned short* A0 = W1f + (size_t)l * 16384 + (size_t)lane * 8;

        f32x16 acc[2][2];
        #pragma unroll
        for (int i = 0; i < 2; ++i)
            #pragma unroll
            for (int j = 0; j < 2; ++j)
                #pragma unroll
                for (int r = 0; r < 16; ++r) acc[i][j][r] = 0.f;

        // ---- K loop: A = W1 fragments (L2), B = x rows (LDS) ----
        #pragma unroll
        for (int ks = 0; ks < 8; ++ks) {
            const int lag = ks >> 2;
            const int cc  = (ks & 3) * 16 + hi32 * 8;
            const unsigned short* p0 = A0 + ks * 1024;
            bf16x8 awh[2], awl[2], bxh[2], bxl[2];
            #pragma unroll
            for (int i = 0; i < 2; ++i) {
                awh[i] = *reinterpret_cast<const bf16x8*>(p0 + i * 8192);
                awl[i] = *reinterpret_cast<const bf16x8*>(p0 + i * 8192 + 512);
            }
            #pragma unroll
            for (int j = 0; j < 2; ++j) {
                const int rr = j * 32 + r32 + lag;
                bxh[j] = *reinterpret_cast<const bf16x8*>(&sXh[rr][cc]);
                bxl[j] = *reinterpret_cast<const bf16x8*>(&sXl[rr][cc]);
            }
            #pragma unroll
            for (int i = 0; i < 2; ++i)
                #pragma unroll
                for (int j = 0; j < 2; ++j) {
                    acc[i][j] = __builtin_amdgcn_mfma_f32_32x32x16_bf16(awh[i], bxh[j], acc[i][j], 0, 0, 0);
                    acc[i][j] = __builtin_amdgcn_mfma_f32_32x32x16_bf16(awh[i], bxl[j], acc[i][j], 0, 0, 0);
                    acc[i][j] = __builtin_amdgcn_mfma_f32_32x32x16_bf16(awl[i], bxh[j], acc[i][j], 0, 0, 0);
                }
        }

        // ---- epilogue: h in (i, g, m, hi32); n = j*32 + r32 ----
        const float xt0 = xg[(xrow0 + 2 + r32) * LATENT + l];
        const float xt1 = xg[(xrow0 + 2 + 32 + r32) * LATENT + l];
        float res0 = 0.f, res1 = 0.f, jp0 = 0.f, jp1 = 0.f, jc = 0.f;
        #pragma unroll
        for (int i = 0; i < 2; ++i)
            #pragma unroll
            for (int g = 0; g < 4; ++g) {
                const int h0 = l * HID + i * 32 + hi32 * 4 + g * 8;
                const f32x4 wt = *reinterpret_cast<const f32x4*>(W1t + h0);
                const f32x4 w2 = *reinterpret_cast<const f32x4*>(W2g + h0);
                const f32x4 b1 = *reinterpret_cast<const f32x4*>(b1g + h0);
                #pragma unroll
                for (int m = 0; m < 4; ++m) {
                    const float c0 = w2[m] * wt[m];
                    jc += c0;
                    const int r = g * 4 + m;
                    const float pre0 = fmaf(xt0, wt[m], acc[i][0][r] + b1[m]);
                    const float pre1 = fmaf(xt1, wt[m], acc[i][1][r] + b1[m]);
                    res0 += w2[m] * fmaxf(pre0, SLOPE * pre0);
                    res1 += w2[m] * fmaxf(pre1, SLOPE * pre1);
                    jp0 += (pre0 >= 0.f) ? c0 : 0.f;
                    jp1 += (pre1 >= 0.f) ? c0 : 0.f;
                }
            }

        res0 += __shfl_xor(res0, 32);
        res1 += __shfl_xor(res1, 32);
        jp0  += __shfl_xor(jp0, 32);
        jp1  += __shfl_xor(jp1, 32);
        jc   += __shfl_xor(jc, 32);
        const float jac0 = SLOPE * jc + (1.f - SLOPE) * jp0;
        const float jac1 = SLOPE * jc + (1.f - SLOPE) * jp1;

        const int lcol = q * 4 + wn;
        if (hi32 == 0) {
            const float b2v = b2g[l];
            sR[r32][lcol]      = res0 + b2v;
            sR[32 + r32][lcol] = res1 + b2v;
        }
        jprod0 *= jac0;
        jprod1 *= jac1;
        if ((q & 3) == 3) {              // log every 4 quads (underflow-safe)
            jlog0 += logf(fabsf(jprod0));  jprod0 = 1.f;
            jlog1 += logf(fabsf(jprod1));  jprod1 = 1.f;
        }
    }

    if (hi32 == 0) {
        sJ[r32][wn]      = jlog0;
        sJ[32 + r32][wn] = jlog1;
    }
    __syncthreads();   // sR/sJ complete

    {   // coalesced residual store: 64 rows x 32 floats, 128B chunks
        const int row = tid >> 2, part = tid & 3;
        *reinterpret_cast<f32x4*>(out_res + (nbase + row) * LATENT + lhalf * 32 + part * 4) =
            *reinterpret_cast<const f32x4*>(&sR[row][part * 4]);
    }
    if (tid < 64) {
        const float part = sJ[tid][0] + sJ[tid][1] + sJ[tid][2] + sJ[tid][3];
        atomicAdd(&out_lad[nbase + tid], part);
    }
}

extern "C" void kernel_launch(void* const* d_in, const int* in_sizes, int n_in,
                              void* d_out, int out_size, void* d_ws, size_t ws_size,
                              hipStream_t stream) {
    const float* xg  = (const float*)d_in[0];
    const float* W1g = (const float*)d_in[1];
    const float* b1g = (const float*)d_in[2];
    const float* W2g = (const float*)d_in[3];
    const float* b2g = (const float*)d_in[4];

    float* out_res = (float*)d_out;
    float* out_lad = out_res + (size_t)NTOT * LATENT;

    float*          W1t = (float*)d_ws;                   // 16 KB
    unsigned short* W1f = (unsigned short*)(W1t + 4096);  // 2 MB fragment-major

    conv_w1<<<512, 256, 0, stream>>>(W1g, W1f, W1t, out_lad);

    dim3 grid(512);  // 256 n-tiles x 2 latent halves = 2 blocks/CU
    fused_mfma<<<grid, 256, 0, stream>>>(xg, b1g, W2g, b2g, W1f, W1t,
                                         out_res, out_lad);
}